// Round 1
// baseline (847.255 us; speedup 1.0000x reference)
//
#include <hip/hip_runtime.h>

// GCN 2-layer forward on MI355X.
// Factorization: norm = dinv[src]*dinv[dst] separates -> pre-scale rows by dinv,
// aggregate as plain segment-sum via CSR gather (no float atomics), post-scale by dinv[dst].
// Row scaling commutes through h @ W, so the scale is fused into epilogues.

// ---------------- CSR build ----------------
__global__ void count_deg_k(const int* __restrict__ dst, int e, int* __restrict__ cnt) {
  int i = blockIdx.x * blockDim.x + threadIdx.x;
  if (i < e) atomicAdd(&cnt[dst[i]], 1);
}

__global__ void scan_blocks_k(const int* __restrict__ in, int n,
                              int* __restrict__ out, int* __restrict__ bsums) {
  __shared__ int s[256];
  const int chunk = 1024;
  int base = blockIdx.x * chunk;
  int t = threadIdx.x;
  int v[4];
  int sum = 0;
#pragma unroll
  for (int i = 0; i < 4; ++i) {
    int idx = base + t * 4 + i;
    int x = (idx < n) ? in[idx] : 0;
    v[i] = sum;
    sum += x;
  }
  s[t] = sum;
  __syncthreads();
  for (int off = 1; off < 256; off <<= 1) {
    int x = 0;
    if (t >= off) x = s[t - off];
    __syncthreads();
    if (t >= off) s[t] += x;
    __syncthreads();
  }
  int excl = (t == 0) ? 0 : s[t - 1];
  if (t == 255) bsums[blockIdx.x] = s[255];
#pragma unroll
  for (int i = 0; i < 4; ++i) {
    int idx = base + t * 4 + i;
    if (idx < n) out[idx] = excl + v[i];
  }
}

__global__ void scan_bsums_k(int* __restrict__ bsums, int nb) {
  __shared__ int s[128];
  int t = threadIdx.x;
  s[t] = (t < nb) ? bsums[t] : 0;
  __syncthreads();
  for (int off = 1; off < 128; off <<= 1) {
    int x = 0;
    if (t >= off) x = s[t - off];
    __syncthreads();
    if (t >= off) s[t] += x;
    __syncthreads();
  }
  if (t < nb) bsums[t] = (t == 0) ? 0 : s[t - 1];
}

__global__ void scan_add_k(int* __restrict__ rs, int* __restrict__ cursor,
                           const int* __restrict__ bsums, int n, int total) {
  int idx = blockIdx.x * blockDim.x + threadIdx.x;
  if (idx < n) {
    int v = rs[idx] + bsums[idx >> 10];
    rs[idx] = v;
    cursor[idx] = v;
  }
  if (idx == 0) rs[n] = total;
}

__global__ void dinv_k(const int* __restrict__ cnt, float* __restrict__ dinv, int n) {
  int i = blockIdx.x * blockDim.x + threadIdx.x;
  if (i < n) dinv[i] = rsqrtf((float)(cnt[i] + 1));  // +1: self-loop; deg>0 always
}

__global__ void scatter_k(const int* __restrict__ src, const int* __restrict__ dst, int e,
                          int* __restrict__ cursor, int* __restrict__ csr) {
  int i = blockIdx.x * blockDim.x + threadIdx.x;
  if (i < e) {
    int d = dst[i];
    int p = atomicAdd(&cursor[d], 1);
    csr[p] = src[i];
  }
}

// ---------------- GEMM: out[n,128] = A[n,K] @ W[K,128], optional row scale ----------------
// 256 threads, 64 rows/block, K-tiles of 32. Each thread: 4 rows x 8 cols.
__global__ __launch_bounds__(256) void gemm_k(const float* __restrict__ A,
                                              const float* __restrict__ W,
                                              const float* __restrict__ rowscale,
                                              float* __restrict__ out, int n, int K) {
  __shared__ float xt[64 * 33];    // [row][k], pad to 33 to avoid bank conflicts
  __shared__ float Wt[32 * 128];   // [k][col]
  int t = threadIdx.x;
  int cg = t & 15, rg = t >> 4;
  int c0 = cg * 8, r0 = rg * 4;
  int row0 = blockIdx.x * 64;

  float acc[4][8];
#pragma unroll
  for (int i = 0; i < 4; ++i)
#pragma unroll
    for (int j = 0; j < 8; ++j) acc[i][j] = 0.f;

  for (int kt = 0; kt < K; kt += 32) {
    for (int l = t; l < 64 * 32; l += 256) {
      int r = l >> 5, kk = l & 31;
      int gr = row0 + r, gk = kt + kk;
      float v = 0.f;
      if (gr < n && gk < K) v = A[(size_t)gr * K + gk];
      xt[r * 33 + kk] = v;
    }
    for (int l = t; l < 32 * 128; l += 256) {
      int kk = l >> 7, c = l & 127;
      int gk = kt + kk;
      Wt[kk * 128 + c] = (gk < K) ? W[(size_t)gk * 128 + c] : 0.f;
    }
    __syncthreads();
#pragma unroll 4
    for (int kk = 0; kk < 32; ++kk) {
      float wv[8];
      *(float4*)&wv[0] = *(const float4*)&Wt[kk * 128 + c0];
      *(float4*)&wv[4] = *(const float4*)&Wt[kk * 128 + c0 + 4];
      float xv[4];
#pragma unroll
      for (int i = 0; i < 4; ++i) xv[i] = xt[(r0 + i) * 33 + kk];
#pragma unroll
      for (int i = 0; i < 4; ++i)
#pragma unroll
        for (int j = 0; j < 8; ++j) acc[i][j] += xv[i] * wv[j];
    }
    __syncthreads();
  }

#pragma unroll
  for (int i = 0; i < 4; ++i) {
    int gr = row0 + r0 + i;
    if (gr < n) {
      float s = rowscale ? rowscale[gr] : 1.0f;
      float o[8];
#pragma unroll
      for (int j = 0; j < 8; ++j) o[j] = acc[i][j] * s;
      *(float4*)&out[(size_t)gr * 128 + c0] = *(const float4*)&o[0];
      *(float4*)&out[(size_t)gr * 128 + c0 + 4] = *(const float4*)&o[4];
    }
  }
}

// ---------------- Aggregation: one wave per node, 2 feats/lane ----------------
// out[i] = relu(dinv[i]*(g[i] + sum_{e: dst=i} g[src[e]]) + bias)
// mode A (Wc==null): store relu(...)*dinv[i]  (pre-scaled input for next GEMM)
// mode B (Wc!=null): classifier epilogue -> out[i*2 + {0,1}] = h . Wc[:,c] + bc[c]
__global__ __launch_bounds__(256) void aggregate_k(const float* __restrict__ g,
                                                   const int* __restrict__ rs,
                                                   const int* __restrict__ csr,
                                                   const float* __restrict__ dinv,
                                                   const float* __restrict__ bias,
                                                   const float* __restrict__ Wc,
                                                   const float* __restrict__ bc,
                                                   float* __restrict__ outv, int n) {
  int wave = threadIdx.x >> 6;
  int lane = threadIdx.x & 63;
  int i = blockIdx.x * 4 + wave;
  if (i >= n) return;
  int f = lane * 2;

  const float* gi = &g[(size_t)i * 128 + f];
  float ax = gi[0], ay = gi[1];  // self term
  int s0 = rs[i], s1 = rs[i + 1];
  for (int e = s0; e < s1; ++e) {
    int s = csr[e];
    const float* gs = &g[(size_t)s * 128 + f];
    ax += gs[0];
    ay += gs[1];
  }
  float di = dinv[i];
  float bx = bias[f], by = bias[f + 1];
  float rx = fmaxf(ax * di + bx, 0.f);
  float ry = fmaxf(ay * di + by, 0.f);

  if (Wc == nullptr) {
    float2 o;
    o.x = rx * di;
    o.y = ry * di;
    *(float2*)&outv[(size_t)i * 128 + f] = o;
  } else {
    // Wc is [128][2]; lane covers features f, f+1 -> Wc[4*lane .. 4*lane+3]
    float4 wv = *(const float4*)&Wc[lane * 4];
    float c0v = rx * wv.x + ry * wv.z;
    float c1v = rx * wv.y + ry * wv.w;
    for (int off = 32; off > 0; off >>= 1) {
      c0v += __shfl_down(c0v, off, 64);
      c1v += __shfl_down(c1v, off, 64);
    }
    if (lane == 0) {
      outv[(size_t)i * 2 + 0] = c0v + bc[0];
      outv[(size_t)i * 2 + 1] = c1v + bc[1];
    }
  }
}

extern "C" void kernel_launch(void* const* d_in, const int* in_sizes, int n_in,
                              void* d_out, int out_size, void* d_ws, size_t ws_size,
                              hipStream_t stream) {
  const float* x  = (const float*)d_in[0];
  const int*   ei = (const int*)d_in[1];
  const float* W1 = (const float*)d_in[2];
  const float* b1 = (const float*)d_in[3];
  const float* W2 = (const float*)d_in[4];
  const float* b2 = (const float*)d_in[5];
  const float* Wc = (const float*)d_in[6];
  const float* bc = (const float*)d_in[7];
  float* out = (float*)d_out;

  const int IN_F = 165;
  const int n = in_sizes[0] / IN_F;  // 100000
  const int e = in_sizes[1] / 2;     // 1600000
  const int* src = ei;
  const int* dst = ei + e;

  char* ws = (char*)d_ws;
  size_t off = 0;
  auto alloc = [&](size_t bytes) -> void* {
    void* p = ws + off;
    off += (bytes + 255) & ~(size_t)255;
    return p;
  };
  float* bufA  = (float*)alloc((size_t)n * 128 * 4);  // 51.2 MB
  float* bufB  = (float*)alloc((size_t)n * 128 * 4);  // 51.2 MB
  int*   csr   = (int*)alloc((size_t)e * 4);          // 6.4 MB
  int*   cnt   = (int*)alloc((size_t)n * 4);
  int*   rs    = (int*)alloc((size_t)(n + 1) * 4);
  int*   cursor= (int*)alloc((size_t)n * 4);
  float* dinv  = (float*)alloc((size_t)n * 4);
  int*   bsums = (int*)alloc(1024);

  hipMemsetAsync(cnt, 0, (size_t)n * 4, stream);

  const int tb = 256;
  count_deg_k<<<(e + tb - 1) / tb, tb, 0, stream>>>(dst, e, cnt);
  int nscan = (n + 1023) / 1024;  // 98 <= 128
  scan_blocks_k<<<nscan, 256, 0, stream>>>(cnt, n, rs, bsums);
  scan_bsums_k<<<1, 128, 0, stream>>>(bsums, nscan);
  scan_add_k<<<(n + tb - 1) / tb, tb, 0, stream>>>(rs, cursor, bsums, n, e);
  dinv_k<<<(n + tb - 1) / tb, tb, 0, stream>>>(cnt, dinv, n);
  scatter_k<<<(e + tb - 1) / tb, tb, 0, stream>>>(src, dst, e, cursor, csr);

  // Layer 1: g1 = (x @ W1) * dinv ; h1s = relu(dinv*(segsum g1) + b1) * dinv
  gemm_k<<<(n + 63) / 64, 256, 0, stream>>>(x, W1, dinv, bufA, n, IN_F);
  aggregate_k<<<(n + 3) / 4, 256, 0, stream>>>(bufA, rs, csr, dinv, b1, nullptr, nullptr, bufB, n);
  // Layer 2: g2 = h1s @ W2 (rows pre-scaled); out = (relu(dinv*(segsum g2)+b2)) @ Wc + bc
  gemm_k<<<(n + 63) / 64, 256, 0, stream>>>(bufB, W2, nullptr, bufA, n, 128);
  aggregate_k<<<(n + 3) / 4, 256, 0, stream>>>(bufA, rs, csr, dinv, b2, Wc, bc, out, n);
}

// Round 2
// 739.710 us; speedup vs baseline: 1.1454x; 1.1454x over previous
//
#include <hip/hip_runtime.h>

// GCN 2-layer forward on MI355X.
// norm = dinv[src]*dinv[dst] separates -> pre-scale rows by dinv, aggregate as a
// plain segment-sum via CSR gather (no float atomics), post-scale by dinv[dst].
// Aggregation: 32 lanes x float4 = one full 128-feat row per half-wave, so each
// load instruction gathers TWO rows; 4-deep predicated unroll => 8 gathers in
// flight per wave (round 1 had 1 -> latency-bound at 2.4 TB/s).

// ---------------- CSR build ----------------
__global__ void count_deg_k(const int* __restrict__ dst, int e, int* __restrict__ cnt) {
  int i = blockIdx.x * blockDim.x + threadIdx.x;
  if (i < e) atomicAdd(&cnt[dst[i]], 1);
}

__global__ void scan_blocks_k(const int* __restrict__ in, int n,
                              int* __restrict__ out, int* __restrict__ bsums) {
  __shared__ int s[256];
  const int chunk = 1024;
  int base = blockIdx.x * chunk;
  int t = threadIdx.x;
  int v[4];
  int sum = 0;
#pragma unroll
  for (int i = 0; i < 4; ++i) {
    int idx = base + t * 4 + i;
    int x = (idx < n) ? in[idx] : 0;
    v[i] = sum;
    sum += x;
  }
  s[t] = sum;
  __syncthreads();
  for (int off = 1; off < 256; off <<= 1) {
    int x = 0;
    if (t >= off) x = s[t - off];
    __syncthreads();
    if (t >= off) s[t] += x;
    __syncthreads();
  }
  int excl = (t == 0) ? 0 : s[t - 1];
  if (t == 255) bsums[blockIdx.x] = s[255];
#pragma unroll
  for (int i = 0; i < 4; ++i) {
    int idx = base + t * 4 + i;
    if (idx < n) out[idx] = excl + v[i];
  }
}

__global__ void scan_bsums_k(int* __restrict__ bsums, int nb) {
  __shared__ int s[128];
  int t = threadIdx.x;
  s[t] = (t < nb) ? bsums[t] : 0;
  __syncthreads();
  for (int off = 1; off < 128; off <<= 1) {
    int x = 0;
    if (t >= off) x = s[t - off];
    __syncthreads();
    if (t >= off) s[t] += x;
    __syncthreads();
  }
  if (t < nb) bsums[t] = (t == 0) ? 0 : s[t - 1];
}

// fused: finalize row starts, init scatter cursors, compute dinv
__global__ void scan_add_k(int* __restrict__ rs, int* __restrict__ cursor,
                           const int* __restrict__ bsums, const int* __restrict__ cnt,
                           float* __restrict__ dinv, int n, int total) {
  int idx = blockIdx.x * blockDim.x + threadIdx.x;
  if (idx < n) {
    int v = rs[idx] + bsums[idx >> 10];
    rs[idx] = v;
    cursor[idx] = v;
    dinv[idx] = rsqrtf((float)(cnt[idx] + 1));  // +1 self-loop
  }
  if (idx == 0) rs[n] = total;
}

__global__ void scatter_k(const int* __restrict__ src, const int* __restrict__ dst, int e,
                          int* __restrict__ cursor, int* __restrict__ csr) {
  int i = blockIdx.x * blockDim.x + threadIdx.x;
  if (i < e) {
    int d = dst[i];
    int p = atomicAdd(&cursor[d], 1);
    csr[p] = src[i];
  }
}

// ---------------- GEMM: out[n,128] = A[n,K] @ W[K,128], optional row scale ----------------
__global__ __launch_bounds__(256) void gemm_k(const float* __restrict__ A,
                                              const float* __restrict__ W,
                                              const float* __restrict__ rowscale,
                                              float* __restrict__ out, int n, int K) {
  __shared__ float xt[64 * 33];    // [row][k], +1 pad
  __shared__ float Wt[32 * 128];   // [k][col]
  int t = threadIdx.x;
  int cg = t & 15, rg = t >> 4;
  int c0 = cg * 8, r0 = rg * 4;
  int row0 = blockIdx.x * 64;

  float acc[4][8];
#pragma unroll
  for (int i = 0; i < 4; ++i)
#pragma unroll
    for (int j = 0; j < 8; ++j) acc[i][j] = 0.f;

  for (int kt = 0; kt < K; kt += 32) {
    for (int l = t; l < 64 * 32; l += 256) {
      int r = l >> 5, kk = l & 31;
      int gr = row0 + r, gk = kt + kk;
      float v = 0.f;
      if (gr < n && gk < K) v = A[(size_t)gr * K + gk];
      xt[r * 33 + kk] = v;
    }
    for (int l = t; l < 32 * 128; l += 256) {
      int kk = l >> 7, c = l & 127;
      int gk = kt + kk;
      Wt[kk * 128 + c] = (gk < K) ? W[(size_t)gk * 128 + c] : 0.f;
    }
    __syncthreads();
#pragma unroll 4
    for (int kk = 0; kk < 32; ++kk) {
      float wv[8];
      *(float4*)&wv[0] = *(const float4*)&Wt[kk * 128 + c0];
      *(float4*)&wv[4] = *(const float4*)&Wt[kk * 128 + c0 + 4];
      float xv[4];
#pragma unroll
      for (int i = 0; i < 4; ++i) xv[i] = xt[(r0 + i) * 33 + kk];
#pragma unroll
      for (int i = 0; i < 4; ++i)
#pragma unroll
        for (int j = 0; j < 8; ++j) acc[i][j] += xv[i] * wv[j];
    }
    __syncthreads();
  }

#pragma unroll
  for (int i = 0; i < 4; ++i) {
    int gr = row0 + r0 + i;
    if (gr < n) {
      float s = rowscale ? rowscale[gr] : 1.0f;
      float o[8];
#pragma unroll
      for (int j = 0; j < 8; ++j) o[j] = acc[i][j] * s;
      *(float4*)&out[(size_t)gr * 128 + c0] = *(const float4*)&o[0];
      *(float4*)&out[(size_t)gr * 128 + c0 + 4] = *(const float4*)&o[4];
    }
  }
}

// ---------------- Aggregation ----------------
// One wave per node. 32 lanes x float4 cover a full 128-feat row; the wave's two
// halves gather DIFFERENT edges (2 rows per load instruction). 4-deep predicated
// unroll => 8 row-gathers in flight. Cross-half shfl_xor(32) combines partials.
// out[i] = relu(dinv[i]*(g[i] + sum g[src]) + bias); mode A stores *dinv[i],
// mode B applies the 128->2 classifier with a width-32 shuffle reduction.
__global__ __launch_bounds__(256) void aggregate_k(const float* __restrict__ g,
                                                   const int* __restrict__ rs,
                                                   const int* __restrict__ csr,
                                                   const float* __restrict__ dinv,
                                                   const float* __restrict__ bias,
                                                   const float* __restrict__ Wc,
                                                   const float* __restrict__ bc,
                                                   float* __restrict__ outv, int n) {
  int wave = threadIdx.x >> 6;
  int lane = threadIdx.x & 63;
  int i = blockIdx.x * 4 + wave;
  if (i >= n) return;
  int half = lane >> 5;      // which edge of the pair
  int l32 = lane & 31;
  int f = l32 * 4;           // this lane's 4 features

  float4 acc = make_float4(0.f, 0.f, 0.f, 0.f);
  int s0 = rs[i], s1 = rs[i + 1];
  int deg = s1 - s0;

  if (deg > 0) {
    int last = s1 - 1;
    for (int eb = s0; eb < s1; eb += 8) {
#pragma unroll
      for (int k = 0; k < 4; ++k) {
        int ee = eb + 2 * k + half;
        float w = (ee <= last) ? 1.f : 0.f;
        int ec = (ee <= last) ? ee : last;
        int srow = csr[ec];
        float4 v = *(const float4*)&g[(size_t)srow * 128 + f];
        acc.x = fmaf(w, v.x, acc.x);
        acc.y = fmaf(w, v.y, acc.y);
        acc.z = fmaf(w, v.z, acc.z);
        acc.w = fmaf(w, v.w, acc.w);
      }
    }
    // combine the two halves (both end holding the full edge sum)
    acc.x += __shfl_xor(acc.x, 32, 64);
    acc.y += __shfl_xor(acc.y, 32, 64);
    acc.z += __shfl_xor(acc.z, 32, 64);
    acc.w += __shfl_xor(acc.w, 32, 64);
  }

  // self term + epilogue (all lanes compute; halves hold duplicates)
  float4 self = *(const float4*)&g[(size_t)i * 128 + f];
  float di = dinv[i];
  float4 bv = *(const float4*)&bias[f];
  float rx = fmaxf((acc.x + self.x) * di + bv.x, 0.f);
  float ry = fmaxf((acc.y + self.y) * di + bv.y, 0.f);
  float rz = fmaxf((acc.z + self.z) * di + bv.z, 0.f);
  float rw = fmaxf((acc.w + self.w) * di + bv.w, 0.f);

  if (Wc == nullptr) {
    if (half == 0) {
      float4 o = make_float4(rx * di, ry * di, rz * di, rw * di);
      *(float4*)&outv[(size_t)i * 128 + f] = o;
    }
  } else {
    // Wc[128][2]; lane covers feats f..f+3 -> Wc[f*2 .. f*2+7]
    float4 w01 = *(const float4*)&Wc[f * 2];
    float4 w23 = *(const float4*)&Wc[f * 2 + 4];
    float c0v = rx * w01.x + ry * w01.z + rz * w23.x + rw * w23.z;
    float c1v = rx * w01.y + ry * w01.w + rz * w23.y + rw * w23.w;
#pragma unroll
    for (int off = 16; off > 0; off >>= 1) {
      c0v += __shfl_down(c0v, off, 32);  // width 32: stays within half
      c1v += __shfl_down(c1v, off, 32);
    }
    if (lane == 0) {
      outv[(size_t)i * 2 + 0] = c0v + bc[0];
      outv[(size_t)i * 2 + 1] = c1v + bc[1];
    }
  }
}

extern "C" void kernel_launch(void* const* d_in, const int* in_sizes, int n_in,
                              void* d_out, int out_size, void* d_ws, size_t ws_size,
                              hipStream_t stream) {
  const float* x  = (const float*)d_in[0];
  const int*   ei = (const int*)d_in[1];
  const float* W1 = (const float*)d_in[2];
  const float* b1 = (const float*)d_in[3];
  const float* W2 = (const float*)d_in[4];
  const float* b2 = (const float*)d_in[5];
  const float* Wc = (const float*)d_in[6];
  const float* bc = (const float*)d_in[7];
  float* out = (float*)d_out;

  const int IN_F = 165;
  const int n = in_sizes[0] / IN_F;  // 100000
  const int e = in_sizes[1] / 2;     // 1600000
  const int* src = ei;
  const int* dst = ei + e;

  char* ws = (char*)d_ws;
  size_t off = 0;
  auto alloc = [&](size_t bytes) -> void* {
    void* p = ws + off;
    off += (bytes + 255) & ~(size_t)255;
    return p;
  };
  float* bufA  = (float*)alloc((size_t)n * 128 * 4);  // 51.2 MB
  float* bufB  = (float*)alloc((size_t)n * 128 * 4);  // 51.2 MB
  int*   csr   = (int*)alloc((size_t)e * 4);          // 6.4 MB
  int*   cnt   = (int*)alloc((size_t)n * 4);
  int*   rs    = (int*)alloc((size_t)(n + 1) * 4);
  int*   cursor= (int*)alloc((size_t)n * 4);
  float* dinv  = (float*)alloc((size_t)n * 4);
  int*   bsums = (int*)alloc(1024);

  hipMemsetAsync(cnt, 0, (size_t)n * 4, stream);

  const int tb = 256;
  count_deg_k<<<(e + tb - 1) / tb, tb, 0, stream>>>(dst, e, cnt);
  int nscan = (n + 1023) / 1024;  // 98 <= 128
  scan_blocks_k<<<nscan, 256, 0, stream>>>(cnt, n, rs, bsums);
  scan_bsums_k<<<1, 128, 0, stream>>>(bsums, nscan);
  scan_add_k<<<(n + tb - 1) / tb, tb, 0, stream>>>(rs, cursor, bsums, cnt, dinv, n, e);
  scatter_k<<<(e + tb - 1) / tb, tb, 0, stream>>>(src, dst, e, cursor, csr);

  // Layer 1: g1 = (x @ W1) * dinv ; h1s = relu(dinv*(segsum g1) + b1) * dinv
  gemm_k<<<(n + 63) / 64, 256, 0, stream>>>(x, W1, dinv, bufA, n, IN_F);
  aggregate_k<<<(n + 3) / 4, 256, 0, stream>>>(bufA, rs, csr, dinv, b1, nullptr, nullptr, bufB, n);
  // Layer 2: g2 = h1s @ W2 (rows pre-scaled); out = relu(dinv*(segsum g2)+b2) @ Wc + bc
  gemm_k<<<(n + 63) / 64, 256, 0, stream>>>(bufB, W2, nullptr, bufA, n, 128);
  aggregate_k<<<(n + 3) / 4, 256, 0, stream>>>(bufA, rs, csr, dinv, b2, Wc, bc, out, n);
}